// Round 2
// baseline (726.865 us; speedup 1.0000x reference)
//
#include <hip/hip_runtime.h>
#include <hip/hip_bf16.h>
#include <stdint.h>

// CrossAttention: B=16 N=4096 M=77 H=8 D=64 QDIM=1024 CDIM=768 INNER=512
// fp32 interface, bf16 MFMA internals, fp32 accumulation.

typedef unsigned short u16;
typedef __bf16 bf16x8 __attribute__((ext_vector_type(8)));
typedef float f32x4 __attribute__((ext_vector_type(4)));

__device__ __forceinline__ void gld_lds16(const void* g, void* l) {
  __builtin_amdgcn_global_load_lds(
      (const __attribute__((address_space(1))) unsigned int*)g,
      (__attribute__((address_space(3))) unsigned int*)l, 16, 0, 0);
}

__device__ __forceinline__ u16 f2bf(float f) {
  __hip_bfloat16 h = __float2bfloat16(f);
  return *reinterpret_cast<u16*>(&h);
}

// x (fp32, contiguous) -> bf16, 8 elems/thread/iter, grid-stride
__global__ void cvt8(const float* __restrict__ in, u16* __restrict__ out,
                     long n8) {
  long i = (long)blockIdx.x * 256 + threadIdx.x;
  const long stride = (long)gridDim.x * 256;
  for (; i < n8; i += stride) {
    f32x4 x0 = *(const f32x4*)(in + i * 8);
    f32x4 x1 = *(const f32x4*)(in + i * 8 + 4);
    union { bf16x8 v; u16 s[8]; } t;
#pragma unroll
    for (int e = 0; e < 4; ++e) {
      t.s[e] = f2bf(x0[e]);
      t.s[e + 4] = f2bf(x1[e]);
    }
    *(bf16x8*)(out + i * 8) = t.v;
  }
}

// out[n*K+k] = bf16(in[k*N+n])  (in: K x N fp32 row-major; out: N x K bf16)
__global__ void wtrans(const float* __restrict__ in, u16* __restrict__ out,
                       int K, int N) {
  int idx = blockIdx.x * 256 + threadIdx.x;
  if (idx < K * N) {
    int n = idx / K, k = idx - n * K;
    out[idx] = f2bf(in[k * N + n]);
  }
}

// vt_all[bh][d][m] = v[b][m][h][d], m clamped to 76 for m in [77,96)
__global__ void vtrans(const u16* __restrict__ kv_all, u16* __restrict__ vt_all) {
  int idx = blockIdx.x * 256 + threadIdx.x;
  if (idx < 16 * 8 * 64 * 96) {
    int m = idx % 96;
    int t = idx / 96;
    int d = t & 63;
    int bh = t >> 6;
    int b = bh >> 3, h = bh & 7;
    int mg = m < 77 ? m : 76;
    vt_all[idx] = kv_all[(size_t)(b * 77 + mg) * 1024 + 512 + h * 64 + d];
  }
}

// ---------- 128x128-tile GEMM (known-good; used for small kv GEMM) ----------
template <bool A_F32, bool C_F32>
__global__ __launch_bounds__(256, 2) void gemm_bt(
    const void* __restrict__ Av, const u16* __restrict__ BT,
    void* __restrict__ Cv, const float* __restrict__ bias,
    int Mr, int K, int Nc) {
  __shared__ u16 Al[128 * 32 * (A_F32 ? 2 : 1)];
  __shared__ u16 Bl[128 * 32];
  const int tid = threadIdx.x;
  const int lane = tid & 63;
  const int wave = tid >> 6;
  const int mlane = lane & 15;
  const int quad = lane >> 4;
  const int m0 = blockIdx.y * 128;
  const int n0 = blockIdx.x * 128;
  const int wm = (wave & 1) * 64;
  const int wn = (wave >> 1) * 64;

  f32x4 acc[4][4];
#pragma unroll
  for (int i = 0; i < 4; ++i)
#pragma unroll
    for (int j = 0; j < 4; ++j) acc[i][j] = (f32x4){0.f, 0.f, 0.f, 0.f};

  const int o0 = tid * 16;

  for (int k0 = 0; k0 < K; k0 += 32) {
    if (A_F32) {
#pragma unroll
      for (int r = 0; r < 4; ++r) {
        const int o = r * 4096 + o0;
        const int row = o >> 7;
        const int colb = o & 127;
        int rg = m0 + row;
        rg = rg < Mr ? rg : (Mr - 1);
        gld_lds16((const char*)Av + ((size_t)rg * K + k0) * 4 + colb,
                  (char*)Al + o);
      }
    } else {
#pragma unroll
      for (int r = 0; r < 2; ++r) {
        const int o = r * 4096 + o0;
        const int row = o >> 6;
        const int colb = o & 63;
        int rg = m0 + row;
        rg = rg < Mr ? rg : (Mr - 1);
        gld_lds16((const char*)Av + ((size_t)rg * K + k0) * 2 + colb,
                  (char*)Al + o);
      }
    }
#pragma unroll
    for (int r = 0; r < 2; ++r) {
      const int o = r * 4096 + o0;
      const int row = o >> 6;
      const int colb = o & 63;
      gld_lds16((const char*)BT + ((size_t)(n0 + row) * K + k0) * 2 + colb,
                (char*)Bl + o);
    }
    __syncthreads();

    bf16x8 af[4], bfr[4];
    if (A_F32) {
      const float* Af = (const float*)Al;
#pragma unroll
      for (int i = 0; i < 4; ++i) {
        const float* ar = Af + (wm + i * 16 + mlane) * 32 + quad * 8;
        f32x4 x0 = *(const f32x4*)ar;
        f32x4 x1 = *(const f32x4*)(ar + 4);
        bf16x8 t;
#pragma unroll
        for (int e = 0; e < 4; ++e) {
          u16 lo = f2bf(x0[e]);
          u16 hi = f2bf(x1[e]);
          t[e] = *reinterpret_cast<__bf16*>(&lo);
          t[e + 4] = *reinterpret_cast<__bf16*>(&hi);
        }
        af[i] = t;
      }
    } else {
      const u16* Ab = (const u16*)Al;
#pragma unroll
      for (int i = 0; i < 4; ++i)
        af[i] = *(const bf16x8*)(Ab + (wm + i * 16 + mlane) * 32 + quad * 8);
    }
#pragma unroll
    for (int j = 0; j < 4; ++j)
      bfr[j] = *(const bf16x8*)(Bl + (wn + j * 16 + mlane) * 32 + quad * 8);
#pragma unroll
    for (int i = 0; i < 4; ++i)
#pragma unroll
      for (int j = 0; j < 4; ++j)
        acc[i][j] = __builtin_amdgcn_mfma_f32_16x16x32_bf16(af[i], bfr[j],
                                                            acc[i][j], 0, 0, 0);
    __syncthreads();
  }

#pragma unroll
  for (int j = 0; j < 4; ++j) {
    const int col = n0 + wn + j * 16 + mlane;
    const float bv = C_F32 ? bias[col] : 0.f;
#pragma unroll
    for (int i = 0; i < 4; ++i) {
      const int rb = m0 + wm + i * 16 + quad * 4;
#pragma unroll
      for (int r = 0; r < 4; ++r) {
        const int row = rb + r;
        if (row < Mr) {
          if (C_F32)
            ((float*)Cv)[(size_t)row * Nc + col] = acc[i][j][r] + bv;
          else
            ((u16*)Cv)[(size_t)row * Nc + col] = f2bf(acc[i][j][r]);
        }
      }
    }
  }
}

// ---------- 8-phase 256x256 GEMM (m201-style), pure bf16 ----------
// BM=BN=256 BK=64, 8 waves (2M x 4N), wave tile 128x64, acc[8][4].
// LDS: 2 buffers x 64 KiB; buffer = A0|A1|B0|B1 half-tiles, each
// [128 rows][64 bf16] = 16 KiB, row stride 128 B, XOR-swizzled
// (read byte ^= (row&7)<<4; global_load_lds source pre-swizzled, dest linear).
// Per K-tile c, 4 phases:
//   j1: ds_read a[f0-3]ks0 + ALL b (12 reads); stage A0(c+1); bar; 16 MFMA; bar
//   j2: ds_read a[f4-7]ks0 (4);               stage A1(c+1); bar; 16 MFMA; bar
//   j3: ds_read a[f0-3]ks1 (4);               stage B1(c+1); bar; 16 MFMA; bar
//   j4: ds_read a[f4-7]ks1 (4);               stage B0(c+2); bar; 16 MFMA;
//       vmcnt(2) [drains c+1's 4 halves, leaves B0(c+2) in flight]; bar
// B is fully consumed at j1 -> B regions free early, making the staging order
// WAR-safe; every half is issued >=2 phases (>1200 cyc) before first use.
// Requires M%256==0, N%256==0, K%64==0, K>=128.

#define ST_A(c_, h_)                                                          \
  {                                                                           \
    const char* g_ = (const char*)A +                                         \
                     (size_t)(m0 + (h_)*128 + srow) * K2 + (size_t)(c_)*128 + \
                     scol;                                                    \
    char* d_ = lds + (((c_)&1) * 65536) + (h_)*16384 + sdst;                  \
    gld_lds16(g_, d_);                                                        \
    gld_lds16(g_ + (size_t)64 * K2, d_ + 8192);                               \
  }

#define ST_B(c_, h_)                                                          \
  {                                                                           \
    const char* g_ = (const char*)BT +                                        \
                     (size_t)(n0 + (h_)*128 + srow) * K2 + (size_t)(c_)*128 + \
                     scol;                                                    \
    char* d_ = lds + (((c_)&1) * 65536) + 32768 + (h_)*16384 + sdst;          \
    gld_lds16(g_, d_);                                                        \
    gld_lds16(g_ + (size_t)64 * K2, d_ + 8192);                               \
  }

#define LD_A(f_, ks_) \
  (*(const bf16x8*)(bufc + aoff + (f_)*2048 + (acol ^ ((ks_)*64))))
#define LD_B(g_, ks_) \
  (*(const bf16x8*)(bufc + boff + (g_)*2048 + (acol ^ ((ks_)*64))))

#define G8_BAR                                                                \
  __builtin_amdgcn_sched_barrier(0);                                          \
  __builtin_amdgcn_s_barrier();                                               \
  __builtin_amdgcn_sched_barrier(0);

#define G8_MFMA(fb_, ks_)                                                     \
  G8_BAR;                                                                     \
  __builtin_amdgcn_s_setprio(1);                                              \
  _Pragma("unroll") for (int f = 0; f < 4; ++f)                               \
      _Pragma("unroll") for (int g = 0; g < 4; ++g) acc[(fb_) + f][g] =       \
          __builtin_amdgcn_mfma_f32_16x16x32_bf16(a[f], b[g][ks_],            \
                                                  acc[(fb_) + f][g], 0, 0, 0);\
  __builtin_amdgcn_s_setprio(0);

template <int NX, bool C_F32>
__global__ __launch_bounds__(512, 2) void gemm8(
    const u16* __restrict__ A, const u16* __restrict__ BT,
    void* __restrict__ Cv, const float* __restrict__ bias,
    const int K, const int Nc) {
  __shared__ __align__(16) char lds[131072];
  const int tid = threadIdx.x;
  const int lane = tid & 63;
  const int wave = tid >> 6;
  const int mlane = lane & 15;
  const int quad = lane >> 4;
  const int wmh = wave >> 2;        // A half-tile index
  const int wn = (wave & 3) * 64;   // n offset within B tile
  const size_t K2 = (size_t)K * 2;

  // XCD-bijective swizzle (nwg % 8 == 0 here), n-fastest for A-stripe L2 reuse
  const int nwg = gridDim.x * gridDim.y;
  const int wg = blockIdx.y * gridDim.x + blockIdx.x;
  const int swz = (wg & 7) * (nwg >> 3) + (wg >> 3);
  const int m0 = (swz / NX) * 256;
  const int n0 = (swz % NX) * 256;
  const int nkt = K >> 6;

  // staging geometry: 8 threads x 16B per 128B row, source pre-swizzled
  const int srow = tid >> 3;
  const int scol = ((tid & 7) * 16) ^ ((srow & 7) << 4);
  const int sdst = tid * 16;

  // frag-read bases
  const int aoff = wmh * 16384 + mlane * 128;
  const int boff = 32768 + (wn >> 7) * 16384 + ((wn & 127) + mlane) * 128;
  const int acol = (quad * 16) ^ ((mlane & 7) << 4);

  f32x4 acc[8][4];
#pragma unroll
  for (int i = 0; i < 8; ++i)
#pragma unroll
    for (int j = 0; j < 4; ++j) acc[i][j] = (f32x4){0.f, 0.f, 0.f, 0.f};

  // prologue: kt0 fully + B0(kt1); wait leaves B0(kt1) in flight
  ST_B(0, 0);
  ST_A(0, 0);
  ST_A(0, 1);
  ST_B(0, 1);
  ST_B(1, 0);
  asm volatile("s_waitcnt vmcnt(2)" ::: "memory");
  G8_BAR;

  for (int c = 0; c < nkt; ++c) {
    const char* bufc = lds + ((c & 1) * 65536);
    const int cp1 = c + 1, cp2 = c + 2;
    bf16x8 a[4];
    bf16x8 b[4][2];

    // ---- j1 ----
#pragma unroll
    for (int f = 0; f < 4; ++f) a[f] = LD_A(f, 0);
#pragma unroll
    for (int g = 0; g < 4; ++g) {
      b[g][0] = LD_B(g, 0);
      b[g][1] = LD_B(g, 1);
    }
    if (cp1 < nkt) ST_A(cp1, 0);
    G8_MFMA(0, 0);
    G8_BAR;

    // ---- j2 ----
#pragma unroll
    for (int f = 0; f < 4; ++f) a[f] = LD_A(4 + f, 0);
    if (cp1 < nkt) ST_A(cp1, 1);
    G8_MFMA(4, 0);
    G8_BAR;

    // ---- j3 ----
#pragma unroll
    for (int f = 0; f < 4; ++f) a[f] = LD_A(f, 1);
    if (cp1 < nkt) ST_B(cp1, 1);
    G8_MFMA(0, 1);
    G8_BAR;

    // ---- j4 ----
#pragma unroll
    for (int f = 0; f < 4; ++f) a[f] = LD_A(4 + f, 1);
    if (cp2 < nkt) ST_B(cp2, 0);
    G8_MFMA(4, 1);
    if (cp2 < nkt) {
      asm volatile("s_waitcnt vmcnt(2)" ::: "memory");
    } else {
      asm volatile("s_waitcnt vmcnt(0)" ::: "memory");
    }
    G8_BAR;
  }

  // epilogue
#pragma unroll
  for (int g = 0; g < 4; ++g) {
    const int col = n0 + wn + g * 16 + mlane;
    const float bv = C_F32 ? bias[col] : 0.f;
#pragma unroll
    for (int f = 0; f < 8; ++f) {
      const int row0 = m0 + wmh * 128 + f * 16 + quad * 4;
#pragma unroll
      for (int r = 0; r < 4; ++r) {
        const size_t off = (size_t)(row0 + r) * Nc + col;
        if (C_F32)
          ((float*)Cv)[off] = acc[f][g][r] + bv;
        else
          ((u16*)Cv)[off] = f2bf(acc[f][g][r]);
      }
    }
  }
}

// ---------- MFMA flash attention (unchanged) ----------
__global__ __launch_bounds__(256, 2) void attn_mfma(
    const u16* __restrict__ q_all,   // (B*4096, 512) bf16
    const u16* __restrict__ kv_all,  // (B*77, 1024) bf16: k | v
    const u16* __restrict__ vt_all,  // (B*H, 64, 96) bf16
    u16* __restrict__ o_all) {       // (B*4096, 512) bf16
  __shared__ u16 Ps[128 * 128];
  const int tid = threadIdx.x;
  const int lane = tid & 63;
  const int wave = tid >> 6;
  const int mlane = lane & 15;
  const int quad = lane >> 4;
  const int b = blockIdx.x >> 3;
  const int h = blockIdx.x & 7;
  const int n0 = blockIdx.y * 128;
  const int wm = wave * 32;

  const u16* qbase =
      q_all + ((size_t)(b * 4096 + n0 + wm)) * 512 + h * 64;
  bf16x8 aq[2][2];
#pragma unroll
  for (int i = 0; i < 2; ++i)
#pragma unroll
    for (int ks = 0; ks < 2; ++ks)
      aq[i][ks] = *(const bf16x8*)(qbase + (size_t)(i * 16 + mlane) * 512 +
                                   ks * 32 + quad * 8);

  bf16x8 bk[5][2];
#pragma unroll
  for (int j = 0; j < 5; ++j) {
    int m = j * 16 + mlane;
    m = m < 77 ? m : 76;
    const u16* kb = kv_all + ((size_t)(b * 77 + m)) * 1024 + h * 64;
#pragma unroll
    for (int ks = 0; ks < 2; ++ks)
      bk[j][ks] = *(const bf16x8*)(kb + ks * 32 + quad * 8);
  }

  f32x4 S[2][5];
#pragma unroll
  for (int i = 0; i < 2; ++i)
#pragma unroll
    for (int j = 0; j < 5; ++j) S[i][j] = (f32x4){0.f, 0.f, 0.f, 0.f};
#pragma unroll
  for (int i = 0; i < 2; ++i)
#pragma unroll
    for (int j = 0; j < 5; ++j)
#pragma unroll
      for (int ks = 0; ks < 2; ++ks)
        S[i][j] = __builtin_amdgcn_mfma_f32_16x16x32_bf16(aq[i][ks], bk[j][ks],
                                                          S[i][j], 0, 0, 0);

  float rs[2][4] = {{0.f, 0.f, 0.f, 0.f}, {0.f, 0.f, 0.f, 0.f}};
#pragma unroll
  for (int i = 0; i < 2; ++i)
#pragma unroll
    for (int j = 0; j < 5; ++j) {
      const int col = j * 16 + mlane;
      const bool valid = col < 77;
#pragma unroll
      for (int r = 0; r < 4; ++r) {
        float e = valid ? __expf(S[i][j][r] * 0.125f) : 0.f;
        S[i][j][r] = e;
        rs[i][r] += e;
      }
    }
#pragma unroll
  for (int i = 0; i < 2; ++i)
#pragma unroll
    for (int r = 0; r < 4; ++r) {
      float v = rs[i][r];
      v += __shfl_xor(v, 1);
      v += __shfl_xor(v, 2);
      v += __shfl_xor(v, 4);
      v += __shfl_xor(v, 8);
      rs[i][r] = 1.f / v;
    }

#pragma unroll
  for (int i = 0; i < 2; ++i)
#pragma unroll
    for (int r = 0; r < 4; ++r) {
      const int row = wm + i * 16 + quad * 4 + r;
      u16* prow = Ps + row * 128;
#pragma unroll
      for (int j = 0; j < 5; ++j) {
        const int col = j * 16 + mlane;
        prow[(((col >> 3) + row) & 15) * 8 + (col & 7)] = f2bf(S[i][j][r]);
      }
      const int colz = 80 + mlane;
      prow[(((colz >> 3) + row) & 15) * 8 + (colz & 7)] = 0;
    }
  __syncthreads();

  const u16* vtb = vt_all + (size_t)blockIdx.x * 64 * 96;
  bf16x8 bv[4][3];
#pragma unroll
  for (int j = 0; j < 4; ++j)
#pragma unroll
    for (int kk = 0; kk < 3; ++kk)
      bv[j][kk] = *(const bf16x8*)(vtb + (j * 16 + mlane) * 96 + kk * 32 +
                                   quad * 8);

  f32x4 O[2][4];
#pragma unroll
  for (int i = 0; i < 2; ++i)
#pragma unroll
    for (int j = 0; j < 4; ++j) O[i][j] = (f32x4){0.f, 0.f, 0.f, 0.f};
#pragma unroll
  for (int i = 0; i < 2; ++i) {
    const int row = wm + i * 16 + mlane;
#pragma unroll
    for (int kk = 0; kk < 3; ++kk) {
      const bf16x8 ap = *(const bf16x8*)(
          Ps + row * 128 + (((kk * 4 + quad) + row) & 15) * 8);
#pragma unroll
      for (int j = 0; j < 4; ++j)
        O[i][j] = __builtin_amdgcn_mfma_f32_16x16x32_bf16(ap, bv[j][kk],
                                                          O[i][j], 0, 0, 0);
    }
  }

  u16* ob = o_all + ((size_t)(b * 4096 + n0 + wm)) * 512 + h * 64;
#pragma unroll
  for (int i = 0; i < 2; ++i)
#pragma unroll
    for (int j = 0; j < 4; ++j)
#pragma unroll
      for (int r = 0; r < 4; ++r) {
        const int rl = i * 16 + quad * 4 + r;
        ob[(size_t)rl * 512 + j * 16 + mlane] = f2bf(O[i][j][r] * rs[i][r]);
      }
}

extern "C" void kernel_launch(void* const* d_in, const int* in_sizes, int n_in,
                              void* d_out, int out_size, void* d_ws,
                              size_t ws_size, hipStream_t stream) {
  const float* x = (const float*)d_in[0];    // (16,4096,1024) fp32
  const float* ctx = (const float*)d_in[1];  // (16,77,768) fp32
  const float* Wq = (const float*)d_in[2];   // (1024,512)
  const float* Wk = (const float*)d_in[3];   // (768,512)
  const float* Wv = (const float*)d_in[4];   // (768,512)
  const float* Wo = (const float*)d_in[5];   // (512,1024)
  const float* bo = (const float*)d_in[6];   // (1024)

  char* p = (char*)d_ws;
  u16* WqT = (u16*)p;  p += (size_t)512 * 1024 * 2;
  u16* WkvT = (u16*)p; p += (size_t)1024 * 768 * 2;
  u16* WoT = (u16*)p;  p += (size_t)1024 * 512 * 2;
  u16* q_all = (u16*)p;    p += (size_t)65536 * 512 * 2;
  u16* kv_all = (u16*)p;   p += (size_t)1232 * 1024 * 2;
  u16* attn_out = (u16*)p; p += (size_t)65536 * 512 * 2;
  u16* vt_all = (u16*)p;   p += (size_t)128 * 64 * 96 * 2;

  // x_bf16 lives in d_out (268 MB fp32 buffer; only written by the final GEMM,
  // and x_bf16's last read precedes that in-stream).
  u16* xb = (u16*)d_out;

  // x -> bf16 (identical rounding to the previous in-kernel cvt path)
  cvt8<<<2048, 256, 0, stream>>>(x, xb, (long)65536 * 1024 / 8);

  wtrans<<<(1024 * 512 + 255) / 256, 256, 0, stream>>>(Wq, WqT, 1024, 512);
  wtrans<<<(768 * 512 + 255) / 256, 256, 0, stream>>>(Wk, WkvT, 768, 512);
  wtrans<<<(768 * 512 + 255) / 256, 256, 0, stream>>>(
      Wv, WkvT + (size_t)512 * 768, 768, 512);
  wtrans<<<(512 * 1024 + 255) / 256, 256, 0, stream>>>(Wo, WoT, 512, 1024);

  // q = x @ Wq : bf16 8-phase, 256x256 tiles (N=512 -> NX=2)
  gemm8<2, false><<<dim3(2, 256), 512, 0, stream>>>(
      xb, WqT, q_all, nullptr, 1024, 512);
  // [k|v] = ctx @ [Wk|Wv] : fp32 A -> bf16 C (small; 128x128 path)
  gemm_bt<true, false><<<dim3(8, 10), 256, 0, stream>>>(
      ctx, WkvT, kv_all, nullptr, 1232, 768, 1024);
  // V^T for the PV MFMA
  vtrans<<<(128 * 64 * 96 + 255) / 256, 256, 0, stream>>>(kv_all, vt_all);
  // attention (MFMA)
  attn_mfma<<<dim3(128, 32), 256, 0, stream>>>(q_all, kv_all, vt_all,
                                               attn_out);
  // out = attn @ Wo + bo : bf16 8-phase, 256x256 tiles (N=1024 -> NX=4)
  gemm8<4, true><<<dim3(4, 256), 512, 0, stream>>>(
      attn_out, WoT, (void*)d_out, bo, 512, 1024);
}